// Round 9
// baseline (486.168 us; speedup 1.0000x reference)
//
#include <hip/hip_runtime.h>
#include <cmath>

typedef __attribute__((ext_vector_type(8))) _Float16 half8;
typedef __attribute__((ext_vector_type(8))) unsigned short ushort8;
typedef __attribute__((ext_vector_type(4))) float f32x4;

#define HH 7168
#define NE 256
#define NQ 224        // K32 chunks
#define NITER 112     // BK=64 iterations
#define TOPK 8
#define TOPKG 4
#define WSC 1024.f
#define INV_WS (1.f/1024.f)
#define C1 (1.f/2048.f)       // 2^-11
#define C2 (1.f/4194304.f)    // 2^-22

// 2-level f16 split: x = h + m*2^-11, residual ~2^-25|x|
__device__ __forceinline__ void split2(float x, unsigned short& h, unsigned short& m){
  const _Float16 hh = (_Float16)x;
  const float r = x - (float)hh;                 // exact
  const _Float16 mm = (_Float16)(r * 2048.f);
  h = __builtin_bit_cast(unsigned short, hh);
  m = __builtin_bit_cast(unsigned short, mm);
}

// W*1024 -> (h,m) f16 in MFMA B-fragment order, coalesced writes.
// slot(q,nt,L) holds B[k=32q+8(L>>4)+j][e=16nt+(L&15)], j=0..7.
__global__ __launch_bounds__(256) void prep_w(const float* __restrict__ wgt,
                                              unsigned short* __restrict__ bh,
                                              unsigned short* __restrict__ bm){
  const int b = blockIdx.x;                 // 896 = 16 nt * 56 q-groups
  const int nt = b & 15, qb = (b >> 4) * 4;
  const int w = threadIdx.x >> 6, L = threadIdx.x & 63;
  const int q = qb + w;
  const int e = nt*16 + (L & 15);
  const int k0 = 32*q + 8*(L >> 4);
  const float4 a0 = *(const float4*)(wgt + (size_t)e*HH + k0);
  const float4 a1 = *(const float4*)(wgt + (size_t)e*HH + k0 + 4);
  const float v[8] = {a0.x,a0.y,a0.z,a0.w,a1.x,a1.y,a1.z,a1.w};
  ushort8 h8, m8;
#pragma unroll
  for(int j=0;j<8;j++){ unsigned short hh,mm; split2(v[j]*WSC, hh, mm); h8[j]=hh; m8[j]=mm; }
  const size_t base = ((size_t)(q*16+nt)*64 + L)*8;
  *(ushort8*)(bh+base) = h8;
  *(ushort8*)(bm+base) = m8;
}

// ---------------- GEMM: B in registers (L2-direct), A-only LDS ----------------
// Block = 32 tok x 128 exp (slice), 512 thr / 8 waves (2mtp x 4ntp), BK=64,
// grid 512 -> 2 blocks/CU (16 waves/CU, 4/SIMD).
// R2 ledger: DS pipe ~140us of 209 (B reads 2/3 + B-DMA writes). Fix: B frags
// load L2->REG via plain C++ half8 loads (prep_w layout is fragment-exact),
// double-buffered in NAMED vars PA/PB (no dyn indexing); B leaves LDS entirely.
// With no B-DMA the barrier needs NO vmem drain: lgkmcnt(0) + raw s_barrier
// (A-LDS publish only) -- B/ga loads stay in flight across barriers.
// Per-accumulator MFMA order + Kahan points identical to R2 -> bit-identical.
#define AB(buf,lvl,mt,q,row) ((((((buf)*2+(lvl))*2+(mt))*2+(q))*64+(row))*16)
__device__ __forceinline__ int swz(int bo){ return bo ^ (((bo >> 8) & 7) << 4); }

#define KAHAN do{ \
  _Pragma("unroll") \
  for(int cc=0;cc<2;cc++) \
    _Pragma("unroll") \
    for(int r=0;r<4;r++){ \
      const float v = c0[cc][r] + c1[cc][r]*C1 + c2[cc][r]*C2; \
      const float y = v - kcmp[cc][r]; \
      const float t = ksum[cc][r] + y; \
      kcmp[cc][r] = (t - ksum[cc][r]) - y; \
      ksum[cc][r] = t; \
    } \
}while(0)

// same per-accumulator sequence as R2's compute loop (ntl=0 then ntl=1)
#define MFMA8(AH,AM,BH0,BH1,BM0,BM1) do{ \
  __builtin_amdgcn_s_setprio(1); \
  c0[0] = __builtin_amdgcn_mfma_f32_16x16x32_f16(AH, BH0, c0[0], 0,0,0); \
  c1[0] = __builtin_amdgcn_mfma_f32_16x16x32_f16(AH, BM0, c1[0], 0,0,0); \
  c1[0] = __builtin_amdgcn_mfma_f32_16x16x32_f16(AM, BH0, c1[0], 0,0,0); \
  c2[0] = __builtin_amdgcn_mfma_f32_16x16x32_f16(AM, BM0, c2[0], 0,0,0); \
  c0[1] = __builtin_amdgcn_mfma_f32_16x16x32_f16(AH, BH1, c0[1], 0,0,0); \
  c1[1] = __builtin_amdgcn_mfma_f32_16x16x32_f16(AH, BM1, c1[1], 0,0,0); \
  c1[1] = __builtin_amdgcn_mfma_f32_16x16x32_f16(AM, BH1, c1[1], 0,0,0); \
  c2[1] = __builtin_amdgcn_mfma_f32_16x16x32_f16(AM, BM1, c2[1], 0,0,0); \
  __builtin_amdgcn_s_setprio(0); \
}while(0)

__global__ __launch_bounds__(512,4)
void gemm(const float* __restrict__ hs,
          const unsigned short* __restrict__ bhp,
          const unsigned short* __restrict__ bmp,
          float* __restrict__ lgout){
  __shared__ __align__(16) unsigned char alds[16384];  // A only: 2buf x 2lvl x 2mt x 2q x 64row x 16B

  const int tid = threadIdx.x, lane = tid & 63, w = tid >> 6;
  const int b = blockIdx.x;
  const int slice = (b >> 2) & 1;          // XCD 0-3 -> slice0, 4-7 -> slice1 (L2-resident)
  const int tg = (b >> 3)*4 + (b & 3);     // 0..255
  const int tb = tg*32, eb = slice*128;
  const int mtp = w >> 2, ntp = w & 3;

  f32x4 ksum[2], kcmp[2], c0[2], c1[2], c2[2];
#pragma unroll
  for(int cc=0;cc<2;cc++){ ksum[cc]=f32x4{0,0,0,0}; kcmp[cc]=f32x4{0,0,0,0}; }

  // A staging ids (threads 0..255 only)
  const int tokS = (tid & 255) >> 3, kidx = tid & 7;
  const int mtS = tokS >> 4, m16S = tokS & 15;
  const int qS = kidx >> 2, kgS = kidx & 3;
  const int rowS = kgS*16 + m16S;
  const float* agp = hs + (size_t)(tb + tokS)*HH + kidx*8;
  float4 ga[2];

  auto stage = [&](int buf){
    unsigned short h[8], m[8];
    const float* gv = (const float*)ga;
#pragma unroll
    for(int p=0;p<8;p++) split2(gv[p], h[p], m[p]);
    ushort8 h8, m8;
#pragma unroll
    for(int j=0;j<8;j++){ h8[j]=h[j]; m8[j]=m[j]; }
    *(ushort8*)&alds[swz(AB(buf,0,mtS,qS,rowS))] = h8;
    *(ushort8*)&alds[swz(AB(buf,1,mtS,qS,rowS))] = m8;
  };

  // B fragment streams (L2-resident, 3.67 MB/slice): wave owns nt pair.
  // slot(q,nt,lane) at bhv[(q*16 + slice*8 + nt)*64 + lane], stride/q = 1024.
  const half8* __restrict__ bhv = (const half8*)bhp;
  const half8* __restrict__ bmv = (const half8*)bmp;
  const int bbase0 = (slice*8 + ntp*2)*64 + lane;       // ntl=0
  const int bbase1 = bbase0 + 64;                        // ntl=1

  // ---- prologue: A chunk 0 staged; B frags q=0 -> PA
  ga[0] = *(const float4*)(agp);
  ga[1] = *(const float4*)(agp + 4);
  stage(0);
  half8 PAh0 = bhv[bbase0], PAh1 = bhv[bbase1];
  half8 PAm0 = bmv[bbase0], PAm1 = bmv[bbase1];
  asm volatile("s_waitcnt lgkmcnt(0)" ::: "memory");
  __builtin_amdgcn_s_barrier();

  half8 PBh0, PBh1, PBm0, PBm1;

#pragma unroll 1
  for(int i=0;i<NITER;i++){
    const int cur = i & 1, nb = cur ^ 1;
    const bool more = (i+1 < NITER);
    if(more){
      const float* ap = agp + (size_t)(i+1)*64;
      ga[0] = *(const float4*)(ap);
      ga[1] = *(const float4*)(ap + 4);
    }
    if((i & 1) == 0){
#pragma unroll
      for(int cc=0;cc<2;cc++){ c0[cc]=f32x4{0,0,0,0}; c1[cc]=f32x4{0,0,0,0}; c2[cc]=f32x4{0,0,0,0}; }
    }
    // ---- s0: q=2i, frags PA; issue PB = frags(2i+1)
    {
      const int s1 = (2*i+1)*1024;
      PBh0 = bhv[s1 + bbase0]; PBh1 = bhv[s1 + bbase1];
      PBm0 = bmv[s1 + bbase0]; PBm1 = bmv[s1 + bbase1];
    }
    {
      const half8 ah = *(const half8*)&alds[swz(AB(cur,0,mtp,0,lane))];
      const half8 am = *(const half8*)&alds[swz(AB(cur,1,mtp,0,lane))];
      MFMA8(ah, am, PAh0, PAh1, PAm0, PAm1);
    }
    // ---- s1: q=2i+1, frags PB; issue PA = frags(2i+2)
    if(more){
      const int s2 = (2*i+2)*1024;
      PAh0 = bhv[s2 + bbase0]; PAh1 = bhv[s2 + bbase1];
      PAm0 = bmv[s2 + bbase0]; PAm1 = bmv[s2 + bbase1];
    }
    {
      const half8 ah = *(const half8*)&alds[swz(AB(cur,0,mtp,1,lane))];
      const half8 am = *(const half8*)&alds[swz(AB(cur,1,mtp,1,lane))];
      MFMA8(ah, am, PBh0, PBh1, PBm0, PBm1);
    }
    if(more) stage(nb);
    if(i & 1) KAHAN;                       // same 128-K flush points as R2 -> bit-identical
    asm volatile("s_waitcnt lgkmcnt(0)" ::: "memory");   // publish A ds_writes only
    __builtin_amdgcn_s_barrier();
  }

  // epilogue: C layout col=lane&15 (expert), row=(lane>>4)*4+r (token); undo W scale
#pragma unroll
  for(int ntl=0;ntl<2;ntl++)
#pragma unroll
    for(int r=0;r<4;r++){
      const int tok = mtp*16 + (lane>>4)*4 + r;
      const int e = (ntp*2+ntl)*16 + (lane&15);
      const float lg = (ksum[ntl][r] - kcmp[ntl][r]) * INV_WS;
      lgout[(size_t)(tb+tok)*NE + eb + e] = lg;
    }
}

// Gating, 1 token per wave, grid T/4.
__global__ __launch_bounds__(256)
void gate(const float* __restrict__ lg, const float* __restrict__ bias,
          float* __restrict__ out, int T){
  const int tid = threadIdx.x, lane = tid & 63, wv = tid >> 6;
  const int t = blockIdx.x*4 + wv;
  const float4 bias4 = *(const float4*)(bias + 4*lane);
  const int g = lane >> 3;
  const float NEG_INF = -__builtin_inff();

  const float4 l4 = *(const float4*)(lg + (size_t)t*NE + 4*lane);
  float4 r4;   // uncorrected sigmoid scores
  r4.x = 1.f/(1.f + expf(-l4.x));
  r4.y = 1.f/(1.f + expf(-l4.y));
  r4.z = 1.f/(1.f + expf(-l4.z));
  r4.w = 1.f/(1.f + expf(-l4.w));
  float4 s4;   // corrected
  s4.x = r4.x + bias4.x; s4.y = r4.y + bias4.y;
  s4.z = r4.z + bias4.z; s4.w = r4.w + bias4.w;

  float m1 = s4.x, m2 = NEG_INF;
  if (s4.y > m1) { m2 = m1; m1 = s4.y; } else if (s4.y > m2) m2 = s4.y;
  if (s4.z > m1) { m2 = m1; m1 = s4.z; } else if (s4.z > m2) m2 = s4.z;
  if (s4.w > m1) { m2 = m1; m1 = s4.w; } else if (s4.w > m2) m2 = s4.w;
#pragma unroll
  for (int m = 1; m <= 4; m <<= 1) {
    const float o1 = __shfl_xor(m1, m);
    const float o2 = __shfl_xor(m2, m);
    const float nm1 = fmaxf(m1, o1);
    const float nm2 = fmaxf(fminf(m1, o1), fmaxf(m2, o2));
    m1 = nm1; m2 = nm2;
  }
  const float gs = m1 + m2;

  float gsv[8];
#pragma unroll
  for (int j = 0; j < 8; ++j) gsv[j] = __shfl(gs, j * 8);

  unsigned gm = 0;
#pragma unroll
  for (int r = 0; r < TOPKG; ++r) {
    float best = NEG_INF; int bj = 0;
#pragma unroll
    for (int j = 0; j < 8; ++j) {
      const bool avail = !((gm >> j) & 1u);
      if (avail && gsv[j] > best) { best = gsv[j]; bj = j; }
    }
    gm |= 1u << bj;
  }
  const bool allowed = (gm >> g) & 1u;

  float v0 = allowed ? s4.x : 0.f;
  float v1 = allowed ? s4.y : 0.f;
  float v2 = allowed ? s4.z : 0.f;
  float v3 = allowed ? s4.w : 0.f;

  float sumw = 0.f;
  int myidx = 0; float myraw = 0.f;
#pragma unroll
  for (int r = 0; r < TOPK; ++r) {
    float bv = v0; int bj = 0;
    if (v1 > bv) { bv = v1; bj = 1; }
    if (v2 > bv) { bv = v2; bj = 2; }
    if (v3 > bv) { bv = v3; bj = 3; }
    int bidx = 4 * lane + bj;
#pragma unroll
    for (int m = 1; m < 64; m <<= 1) {
      const float ov = __shfl_xor(bv, m);
      const int   oi = __shfl_xor(bidx, m);
      if (ov > bv || (ov == bv && oi < bidx)) { bv = ov; bidx = oi; }
    }
    const int oj = bidx & 3;
    const float cand = (oj == 0) ? r4.x
                     : (oj == 1) ? r4.y
                     : (oj == 2) ? r4.z
                     :             r4.w;
    const float raw = __shfl(cand, bidx >> 2);
    sumw += raw;
    if (lane == r) { myidx = bidx; myraw = raw; }
    if (lane == (bidx >> 2)) {
      if      (oj == 0) v0 = NEG_INF;
      else if (oj == 1) v1 = NEG_INF;
      else if (oj == 2) v2 = NEG_INF;
      else              v3 = NEG_INF;
    }
  }

  if (lane < TOPK) {
    out[(size_t)t * TOPK + lane] = (float)myidx;
    out[(size_t)T * TOPK + (size_t)t * TOPK + lane] = myraw / (sumw + 1e-20f) * 2.5f;
  }
}

extern "C" void kernel_launch(void* const* d_in, const int* in_sizes, int n_in,
                              void* d_out, int out_size, void* d_ws, size_t ws_size,
                              hipStream_t stream) {
  const float* hs   = (const float*)d_in[0];
  const float* wgt  = (const float*)d_in[1];
  const float* bias = (const float*)d_in[2];
  float* out = (float*)d_out;

  const int T = in_sizes[0] / HH;   // 8192

  unsigned short* bh = (unsigned short*)d_ws;
  unsigned short* bm = bh + (size_t)NE*HH;
  float* lgbuf = (float*)(bm + (size_t)NE*HH);   // 8.4 MB; total ws use 15.7 MB

  hipLaunchKernelGGL(prep_w, dim3(896), dim3(256), 0, stream, wgt, bh, bm);
  hipLaunchKernelGGL(gemm,   dim3(512), dim3(512), 0, stream, hs, bh, bm, lgbuf);
  hipLaunchKernelGGL(gate,   dim3(T/4), dim3(256), 0, stream, lgbuf, bias, out, T);
}